// Round 7
// baseline (401.928 us; speedup 1.0000x reference)
//
#include <hip/hip_runtime.h>
#include <hip/hip_bf16.h>
#include <math.h>

#define N_NODES 100000
#define DIM 128
#define NH 8
#define NC 16
#define E_EDGES 400000
#define LN_EPS 1e-3f
#define SCAN_B 1024
#define PROJ_GRID 512

typedef __attribute__((ext_vector_type(8))) short short8v;
typedef __attribute__((ext_vector_type(4))) short short4v;
typedef __attribute__((ext_vector_type(4))) float float4v;

__device__ __forceinline__ short bf16bits(float v) {
    __hip_bfloat16 b = __float2bfloat16(v);
    return *(short*)&b;
}

// unpack a uint holding 2 bf16 (lo, hi) into 2 floats
__device__ __forceinline__ void bf2x2(unsigned v, float& a, float& b) {
    a = __uint_as_float(v << 16);
    b = __uint_as_float(v & 0xffff0000u);
}

// ---------------- fused transposed weights (bf16) + fused biases -------------
// Wt[c][d], c in [0,768): sections of 128 cols:
//  0: Wk·BD(Watt0)·prior0/sqrt(C)   1: Wk·BD(Watt1)·prior1/sqrt(C)
//  2: Wm·BD(Wmsg0)                  3: Wm·BD(Wmsg1)
//  4: Wq                            5: Wa
__global__ __launch_bounds__(128) void fuse_weights(
    const float* __restrict__ Wk, const float* __restrict__ bk,
    const float* __restrict__ Wm, const float* __restrict__ bm,
    const float* __restrict__ Wq, const float* __restrict__ bq,
    const float* __restrict__ Wa, const float* __restrict__ ba,
    const float* __restrict__ Watt0, const float* __restrict__ Wmsg0,
    const float* __restrict__ Watt1, const float* __restrict__ Wmsg1,
    const float* __restrict__ prior0, const float* __restrict__ prior1,
    __hip_bfloat16* __restrict__ Wt, float* __restrict__ bias)
{
    const int c = blockIdx.x;        // 0..767
    const int d = threadIdx.x;       // 0..127
    const int sec = c >> 7, j = c & 127, h = j >> 4, l = j & 15;
    float v, b;
    if (sec == 4)      { v = Wq[d * DIM + j]; b = bq[j]; }
    else if (sec == 5) { v = Wa[d * DIM + j]; b = ba[j]; }
    else {
        const float* W1 = (sec < 2) ? Wk : Wm;
        const float* bs = (sec < 2) ? bk : bm;
        const float* W2 = (sec == 0) ? Watt0 : (sec == 1) ? Watt1
                          : (sec == 2) ? Wmsg0 : Wmsg1;
        float scale = (sec == 0) ? prior0[h] * 0.25f
                    : (sec == 1) ? prior1[h] * 0.25f : 1.f;
        float s = 0.f, sb = 0.f;
        #pragma unroll
        for (int kk = 0; kk < NC; ++kk) {
            float w2 = W2[h * 256 + kk * 16 + l];
            s  = fmaf(W1[d * DIM + h * 16 + kk], w2, s);
            sb = fmaf(bs[h * 16 + kk], w2, sb);
        }
        v = s * scale; b = sb * scale;
    }
    Wt[(size_t)c * DIM + d] = __float2bfloat16(v);
    if (d == 0) bias[c] = b;
}

// ---------------- proj: bf16 MFMA GEMM [N,128]@[128,640] ---------------------
// Persistent grid-stride kernel, 8 waves (512 thr), W register-resident.
// Outputs: ka[2N][128], mg[2N][128], qb[N][128] (plain row-major bf16).
__global__ __launch_bounds__(512) void proj_mfma(
    const float* __restrict__ x,             // [N][128] fp32
    const __hip_bfloat16* __restrict__ Wt,   // [768][128]
    const float* __restrict__ bias,          // [768]
    __hip_bfloat16* __restrict__ ka,         // [2N][128]
    __hip_bfloat16* __restrict__ mg,         // [2N][128]
    __hip_bfloat16* __restrict__ qb)         // [N][128]
{
    __shared__ __align__(16) short xs[2][32 * DIM];   // 2 x 8 KB
    const int tid = threadIdx.x;
    const int wave = tid >> 6, lane = tid & 63;
    const int quad = lane >> 4, mcol = lane & 15;
    const int nt = N_NODES / 32;                      // 3125

    // ---- hoist W fragments + bias into registers (once) -------------------
    short8v wf[5][4];
    float4v bv[5];
    #pragma unroll
    for (int s = 0; s < 5; ++s) {
        const int c0 = s * 128 + wave * 16;
        const short* wp = (const short*)Wt + (size_t)(c0 + mcol) * DIM + quad * 8;
        #pragma unroll
        for (int kb = 0; kb < 4; ++kb)
            wf[s][kb] = *(const short8v*)(wp + kb * 32);
        bv[s] = *(const float4v*)(bias + c0 + quad * 4);
    }

    // ---- staging geometry: thread -> (row 0..31, 16B chunk 0..15) ----------
    const int srow = tid >> 4, sc8 = tid & 15;
    const int swz = ((sc8 ^ (srow & 7)) * 8);         // XOR-swizzled chunk

    int t = blockIdx.x;
    if (t >= nt) return;

    // prologue: stage tile t into buf0, prefetch tile t+G into regs
    float4v f0 = *(const float4v*)(x + (size_t)(t * 32 + srow) * DIM + sc8 * 8);
    float4v f1 = *(const float4v*)(x + (size_t)(t * 32 + srow) * DIM + sc8 * 8 + 4);
    {
        short8v sv;
        #pragma unroll
        for (int j = 0; j < 4; ++j) { sv[j] = bf16bits(f0[j]); sv[j + 4] = bf16bits(f1[j]); }
        *(short8v*)(xs[0] + srow * DIM + swz) = sv;
    }
    {
        int nn = t + PROJ_GRID;
        if (nn < nt) {
            f0 = *(const float4v*)(x + (size_t)(nn * 32 + srow) * DIM + sc8 * 8);
            f1 = *(const float4v*)(x + (size_t)(nn * 32 + srow) * DIM + sc8 * 8 + 4);
        }
    }

    int cur = 0;
    for (; t < nt; t += PROJ_GRID) {
        __syncthreads();   // buf[cur] fully staged; prev iter's reads complete

        // B fragments (x^T) for 32 rows: node = mcol (+16), k = quad*8 + j
        short8v b0[4], b1[4];
        #pragma unroll
        for (int kb = 0; kb < 4; ++kb) {
            const int ch = ((quad + kb * 4) ^ (mcol & 7)) * 8;
            b0[kb] = *(const short8v*)(xs[cur] + mcol * DIM + ch);
            b1[kb] = *(const short8v*)(xs[cur] + (mcol + 16) * DIM + ch);
        }

        const int r0 = t * 32;
        #pragma unroll
        for (int s = 0; s < 5; ++s) {
            float4v acc0 = {0.f, 0.f, 0.f, 0.f};
            float4v acc1 = {0.f, 0.f, 0.f, 0.f};
            #pragma unroll
            for (int kb = 0; kb < 4; ++kb) {
                acc0 = __builtin_amdgcn_mfma_f32_16x16x32_bf16(wf[s][kb], b0[kb], acc0, 0, 0, 0);
                acc1 = __builtin_amdgcn_mfma_f32_16x16x32_bf16(wf[s][kb], b1[kb], acc1, 0, 0, 0);
            }
            __hip_bfloat16* dst =
                (s == 0) ? ka :
                (s == 1) ? ka + (size_t)N_NODES * DIM :
                (s == 2) ? mg :
                (s == 3) ? mg + (size_t)N_NODES * DIM :
                           qb;
            short* dp = (short*)dst + (size_t)(r0 + mcol) * DIM + wave * 16 + quad * 4;
            short4v o0, o1;
            #pragma unroll
            for (int g = 0; g < 4; ++g) {
                o0[g] = bf16bits(acc0[g] + bv[s][g]);
                o1[g] = bf16bits(acc1[g] + bv[s][g]);
            }
            *(short4v*)dp              = o0;
            *(short4v*)(dp + 16 * DIM) = o1;
        }

        // stage tile t+G (already in f0/f1) into buf[cur^1]; prefetch t+2G
        int nn = t + PROJ_GRID;
        if (nn < nt) {
            short8v sv;
            #pragma unroll
            for (int j = 0; j < 4; ++j) { sv[j] = bf16bits(f0[j]); sv[j + 4] = bf16bits(f1[j]); }
            *(short8v*)(xs[cur ^ 1] + srow * DIM + swz) = sv;
            int n2 = nn + PROJ_GRID;
            if (n2 < nt) {
                f0 = *(const float4v*)(x + (size_t)(n2 * 32 + srow) * DIM + sc8 * 8);
                f1 = *(const float4v*)(x + (size_t)(n2 * 32 + srow) * DIM + sc8 * 8 + 4);
            }
        }
        cur ^= 1;
    }
}

// ---------------- CSR build ----------------
__global__ __launch_bounds__(256) void hist_kernel(
    const int* __restrict__ dst0, const int* __restrict__ dst1,
    int* __restrict__ counts)
{
    int e = blockIdx.x * 256 + threadIdx.x;
    if (e < E_EDGES) atomicAdd(&counts[dst0[e]], 1);
    int e1 = e - E_EDGES;
    if (e1 >= 0 && e1 < E_EDGES) atomicAdd(&counts[dst1[e1]], 1);
}

__global__ __launch_bounds__(SCAN_B) void scanA_kernel(
    const int* __restrict__ counts, int* __restrict__ row_ptr,
    int* __restrict__ bsum)
{
    __shared__ int buf[2][SCAN_B];
    int i = blockIdx.x * SCAN_B + threadIdx.x;
    int v = (i < N_NODES) ? counts[i] : 0;
    int cur = 0;
    buf[0][threadIdx.x] = v;
    __syncthreads();
    #pragma unroll
    for (int off = 1; off < SCAN_B; off <<= 1) {
        int t = buf[cur][threadIdx.x];
        int add = (threadIdx.x >= off) ? buf[cur][threadIdx.x - off] : 0;
        buf[cur ^ 1][threadIdx.x] = t + add;
        cur ^= 1;
        __syncthreads();
    }
    int inc = buf[cur][threadIdx.x];
    if (i < N_NODES) row_ptr[i] = inc - v;
    if (threadIdx.x == SCAN_B - 1) bsum[blockIdx.x] = inc;
}

// parallel exclusive scan of the (<=128) block sums, single block
__global__ __launch_bounds__(128) void scanB_kernel(int* __restrict__ bsum, int nblocks)
{
    __shared__ int buf[2][128];
    int t = threadIdx.x;
    int v = (t < nblocks) ? bsum[t] : 0;
    buf[0][t] = v;
    __syncthreads();
    int cur = 0;
    #pragma unroll
    for (int off = 1; off < 128; off <<= 1) {
        int a = buf[cur][t];
        if (t >= off) a += buf[cur][t - off];
        buf[cur ^ 1][t] = a;
        cur ^= 1;
        __syncthreads();
    }
    if (t < nblocks) bsum[t] = buf[cur][t] - v;   // exclusive
}

__global__ __launch_bounds__(SCAN_B) void scanC_kernel(
    int* __restrict__ row_ptr, int* __restrict__ cursor,
    const int* __restrict__ bsum)
{
    int i = blockIdx.x * SCAN_B + threadIdx.x;
    if (i < N_NODES) {
        int r = row_ptr[i] + bsum[blockIdx.x];
        row_ptr[i] = r;
        cursor[i] = r;
    }
}

__global__ __launch_bounds__(256) void scatter_kernel(
    const int* __restrict__ src0, const int* __restrict__ dst0,
    const int* __restrict__ src1, const int* __restrict__ dst1,
    int* __restrict__ cursor, unsigned int* __restrict__ eidx)
{
    int e = blockIdx.x * 256 + threadIdx.x;
    if (e < E_EDGES) {
        int d = dst0[e];
        int pos = atomicAdd(&cursor[d], 1);
        eidx[pos] = (unsigned int)src0[e];
    }
    int e1 = e - E_EDGES;
    if (e1 >= 0 && e1 < E_EDGES) {
        int d = dst1[e1];
        int pos = atomicAdd(&cursor[d], 1);
        eidx[pos] = (unsigned int)(src1[e1] + N_NODES);
    }
}

// ---------------- pass A: scores ---------------------------------------------
// Wave per node; lanes 0-31 edge a, 32-63 edge b. Lane gathers 8B (4 ch) of
// the ka row (51 MB hot set), dots with q, 2-shuffle head reduce, exp.
// Writes raw exp weights w[e][h] (bf16, CSR order) and inv-denominator
// (normalization commutes: pooled = (sum w*m) * invden).
__global__ __launch_bounds__(256) void score_kernel(
    const char* __restrict__ ka,        // [2N][256B]
    const uint2* __restrict__ qv,       // [N][32] uint2 (4 ch per lane)
    const int* __restrict__ row_ptr, const int* __restrict__ counts,
    const unsigned int* __restrict__ eidx,
    __hip_bfloat16* __restrict__ w,     // [2E][8]
    float* __restrict__ invden)         // [N][8]
{
    const int wave = threadIdx.x >> 6, lane = threadIdx.x & 63;
    const int n = blockIdx.x * 4 + wave;
    if (n >= N_NODES) return;
    const int start = row_ptr[n], cnt = counts[n];
    const int hi = lane >> 5;
    const int glane = lane & 31;
    const unsigned g8 = (unsigned)glane << 3;
    const int head = glane >> 2;
    const bool wlane = ((glane & 3) == 0);

    uint2 qu = qv[(size_t)n * 32 + glane];
    float q0, q1, q2, q3;
    bf2x2(qu.x, q0, q1); bf2x2(qu.y, q2, q3);

    float den = 0.f;

#define SC_CONS(u, pos)                                                      \
    {                                                                        \
        float k0, k1, k2, k3;                                                \
        bf2x2((u).x, k0, k1); bf2x2((u).y, k2, k3);                          \
        float p = fmaf(k3, q3, fmaf(k2, q2, fmaf(k1, q1, k0 * q0)));         \
        p += __shfl_xor(p, 1, 64);                                           \
        p += __shfl_xor(p, 2, 64);                                           \
        float e = __expf(p);                                                 \
        den += e;                                                            \
        if (wlane) w[(size_t)(pos) * 8 + head] = __float2bfloat16(e);        \
    }

    int i = 0;
    for (; i + 8 <= cnt; i += 8) {
        unsigned ra = eidx[start + i + hi];
        unsigned rb = eidx[start + i + 2 + hi];
        unsigned rc = eidx[start + i + 4 + hi];
        unsigned rd = eidx[start + i + 6 + hi];
        uint2 ua = *(const uint2*)(ka + (((size_t)ra << 8) | g8));
        uint2 ub = *(const uint2*)(ka + (((size_t)rb << 8) | g8));
        uint2 uc = *(const uint2*)(ka + (((size_t)rc << 8) | g8));
        uint2 ud = *(const uint2*)(ka + (((size_t)rd << 8) | g8));
        SC_CONS(ua, start + i + hi);
        SC_CONS(ub, start + i + 2 + hi);
        SC_CONS(uc, start + i + 4 + hi);
        SC_CONS(ud, start + i + 6 + hi);
    }
    for (; i + 2 <= cnt; i += 2) {
        unsigned ra = eidx[start + i + hi];
        uint2 ua = *(const uint2*)(ka + (((size_t)ra << 8) | g8));
        SC_CONS(ua, start + i + hi);
    }
    if (i < cnt) {   // odd tail: both halves compute same edge; hi contributes 0
        unsigned ra = eidx[start + i];
        uint2 ua = *(const uint2*)(ka + (((size_t)ra << 8) | g8));
        float k0, k1, k2, k3;
        bf2x2(ua.x, k0, k1); bf2x2(ua.y, k2, k3);
        float p = fmaf(k3, q3, fmaf(k2, q2, fmaf(k1, q1, k0 * q0)));
        p += __shfl_xor(p, 1, 64);
        p += __shfl_xor(p, 2, 64);
        float e = hi ? 0.f : __expf(p);
        den += e;
        if (wlane && !hi) w[(size_t)(start + i) * 8 + head] = __float2bfloat16(e);
    }
#undef SC_CONS

    den += __shfl_xor(den, 32, 64);
    if (!hi && wlane) {
        float inv = (den > 0.f) ? (1.f / den) : 0.f;
        invden[(size_t)n * 8 + head] = inv;
    }
}

// ---------------- pass B: weighted sum + gelu --------------------------------
// Wave per node; pair scheme. Lane gathers 8B of the mg row (51 MB hot set)
// + its head's weight; 4 FMA/edge. Combine halves once per node, scale by
// invden, gelu, write pooled.
__global__ __launch_bounds__(256) void sum_kernel(
    const char* __restrict__ mg,          // [2N][256B]
    const __hip_bfloat16* __restrict__ w, // [2E][8]
    const float* __restrict__ invden,     // [N][8]
    const int* __restrict__ row_ptr, const int* __restrict__ counts,
    const unsigned int* __restrict__ eidx,
    uint2* __restrict__ pooled)           // [N][32]
{
    const int wave = threadIdx.x >> 6, lane = threadIdx.x & 63;
    const int n = blockIdx.x * 4 + wave;
    if (n >= N_NODES) return;
    const int start = row_ptr[n], cnt = counts[n];
    const int hi = lane >> 5;
    const int glane = lane & 31;
    const unsigned g8 = (unsigned)glane << 3;
    const int head = glane >> 2;

    float a0 = 0.f, a1 = 0.f, a2 = 0.f, a3 = 0.f;

#define SM_CONS(u, wv_)                                                      \
    {                                                                        \
        float m0, m1, m2, m3;                                                \
        bf2x2((u).x, m0, m1); bf2x2((u).y, m2, m3);                          \
        a0 = fmaf(wv_, m0, a0); a1 = fmaf(wv_, m1, a1);                      \
        a2 = fmaf(wv_, m2, a2); a3 = fmaf(wv_, m3, a3);                      \
    }

    int i = 0;
    for (; i + 8 <= cnt; i += 8) {
        unsigned ra = eidx[start + i + hi];
        unsigned rb = eidx[start + i + 2 + hi];
        unsigned rc = eidx[start + i + 4 + hi];
        unsigned rd = eidx[start + i + 6 + hi];
        uint2 ua = *(const uint2*)(mg + (((size_t)ra << 8) | g8));
        uint2 ub = *(const uint2*)(mg + (((size_t)rb << 8) | g8));
        uint2 uc = *(const uint2*)(mg + (((size_t)rc << 8) | g8));
        uint2 ud = *(const uint2*)(mg + (((size_t)rd << 8) | g8));
        float wa = __bfloat162float(w[(size_t)(start + i + hi) * 8 + head]);
        float wb = __bfloat162float(w[(size_t)(start + i + 2 + hi) * 8 + head]);
        float wc = __bfloat162float(w[(size_t)(start + i + 4 + hi) * 8 + head]);
        float wd = __bfloat162float(w[(size_t)(start + i + 6 + hi) * 8 + head]);
        SM_CONS(ua, wa); SM_CONS(ub, wb); SM_CONS(uc, wc); SM_CONS(ud, wd);
    }
    for (; i + 2 <= cnt; i += 2) {
        unsigned ra = eidx[start + i + hi];
        uint2 ua = *(const uint2*)(mg + (((size_t)ra << 8) | g8));
        float wa = __bfloat162float(w[(size_t)(start + i + hi) * 8 + head]);
        SM_CONS(ua, wa);
    }
    if (i < cnt) {   // odd tail
        unsigned ra = eidx[start + i];
        uint2 ua = *(const uint2*)(mg + (((size_t)ra << 8) | g8));
        float wa = hi ? 0.f
                      : __bfloat162float(w[(size_t)(start + i) * 8 + head]);
        SM_CONS(ua, wa);
    }
#undef SM_CONS

    a0 += __shfl_xor(a0, 32, 64);
    a1 += __shfl_xor(a1, 32, 64);
    a2 += __shfl_xor(a2, 32, 64);
    a3 += __shfl_xor(a3, 32, 64);

    const float inv = invden[(size_t)n * 8 + head];
    float v0 = a0 * inv, v1 = a1 * inv, v2 = a2 * inv, v3 = a3 * inv;

    // 2 erf/lane: lo half gelus (v0,v1), hi half (v2,v3); exchange via shfl
    float s0 = hi ? v2 : v0;
    float s1 = hi ? v3 : v1;
    s0 = 0.5f * s0 * (1.f + erff(s0 * 0.70710678118654752f));
    s1 = 0.5f * s1 * (1.f + erff(s1 * 0.70710678118654752f));
    unsigned pk = ((unsigned)(unsigned short)bf16bits(s0))
                | ((unsigned)(unsigned short)bf16bits(s1) << 16);
    unsigned ph = __shfl_xor(pk, 32, 64);
    if (!hi) {
        uint2 o; o.x = pk; o.y = ph;
        pooled[(size_t)n * 32 + glane] = o;
    }
}

// ---------------- final: MFMA GEMM(Wa) -> skip -> LayerNorm ------------------
__global__ __launch_bounds__(256) void final_mfma(
    const __hip_bfloat16* __restrict__ pooled,  // [N][128] bf16, gelu applied
    const __hip_bfloat16* __restrict__ Wt,      // [768][128]; rows 640.. = Wa^T
    const float* __restrict__ bias,             // [768]; 640.. = ba
    const float* __restrict__ x,
    const float* __restrict__ skip, const float* __restrict__ gamma,
    const float* __restrict__ beta, float* __restrict__ out)
{
    __shared__ float hs[32][DIM];
    const int wave = threadIdx.x >> 6, lane = threadIdx.x & 63;
    const int quad = lane >> 4, mcol = lane & 15;
    const int r0 = blockIdx.x * 32;

    short8v a0[4], a1[4];
    const short* pp0 = (const short*)pooled + (size_t)(r0 + mcol) * DIM + quad * 8;
    const short* pp1 = pp0 + 16 * DIM;
    #pragma unroll
    for (int kb = 0; kb < 4; ++kb) {
        a0[kb] = *(const short8v*)(pp0 + kb * 32);
        a1[kb] = *(const short8v*)(pp1 + kb * 32);
    }
    const float alpha = 1.f / (1.f + expf(-skip[0]));

    #pragma unroll
    for (int t = 0; t < 2; ++t) {
        const int c0 = wave * 32 + t * 16;
        const short* wp = (const short*)Wt + (size_t)(640 + c0 + mcol) * DIM + quad * 8;
        float4v acc0 = {0.f, 0.f, 0.f, 0.f};
        float4v acc1 = {0.f, 0.f, 0.f, 0.f};
        #pragma unroll
        for (int kb = 0; kb < 4; ++kb) {
            short8v bfr = *(const short8v*)(wp + kb * 32);
            acc0 = __builtin_amdgcn_mfma_f32_16x16x32_bf16(a0[kb], bfr, acc0, 0, 0, 0);
            acc1 = __builtin_amdgcn_mfma_f32_16x16x32_bf16(a1[kb], bfr, acc1, 0, 0, 0);
        }
        const float bcol = bias[640 + c0 + mcol];
        const int cc = c0 + mcol;
        const int rq = quad * 4;
        #pragma unroll
        for (int g = 0; g < 4; ++g) {
            int rA = rq + g, rB = rq + 16 + g;
            hs[rA][cc] = alpha * (acc0[g] + bcol)
                       + (1.f - alpha) * x[(size_t)(r0 + rA) * DIM + cc];
            hs[rB][cc] = alpha * (acc1[g] + bcol)
                       + (1.f - alpha) * x[(size_t)(r0 + rB) * DIM + cc];
        }
    }
    __syncthreads();

    float gam0 = gamma[lane], gam1 = gamma[lane + 64];
    float bet0 = beta[lane],  bet1 = beta[lane + 64];
    for (int r = wave; r < 32; r += 4) {
        int row = r0 + r;
        float v0 = hs[r][lane], v1 = hs[r][lane + 64];
        float s = v0 + v1, s2 = v0 * v0 + v1 * v1;
        #pragma unroll
        for (int off = 1; off < 64; off <<= 1) {
            s  += __shfl_xor(s,  off, 64);
            s2 += __shfl_xor(s2, off, 64);
        }
        float mu = s * (1.f / 128.f);
        float var = s2 * (1.f / 128.f) - mu * mu;
        float rstd = rsqrtf(var + LN_EPS);
        out[(size_t)row * DIM + lane]      = (v0 - mu) * rstd * gam0 + bet0;
        out[(size_t)row * DIM + lane + 64] = (v1 - mu) * rstd * gam1 + bet1;
    }
}

extern "C" void kernel_launch(void* const* d_in, const int* in_sizes, int n_in,
                              void* d_out, int out_size, void* d_ws, size_t ws_size,
                              hipStream_t stream) {
    const float* x     = (const float*)d_in[0];
    const int*   src0  = (const int*)d_in[1];
    const int*   dst0  = (const int*)d_in[2];
    const int*   src1  = (const int*)d_in[3];
    const int*   dst1  = (const int*)d_in[4];
    const float* Wk    = (const float*)d_in[5];
    const float* bk    = (const float*)d_in[6];
    const float* Wm    = (const float*)d_in[7];
    const float* bm    = (const float*)d_in[8];
    const float* Wq    = (const float*)d_in[9];
    const float* bq    = (const float*)d_in[10];
    const float* Wa    = (const float*)d_in[11];
    const float* ba    = (const float*)d_in[12];
    const float* Watt0 = (const float*)d_in[13];
    const float* Wmsg0 = (const float*)d_in[14];
    const float* Watt1 = (const float*)d_in[15];
    const float* Wmsg1 = (const float*)d_in[16];
    const float* prior0= (const float*)d_in[17];
    const float* prior1= (const float*)d_in[18];
    const float* skip  = (const float*)d_in[19];
    const float* gamma = (const float*)d_in[20];
    const float* beta  = (const float*)d_in[21];
    float* out = (float*)d_out;

    const size_t nd = (size_t)N_NODES * DIM;
    // Workspace (~149 MB):
    //   Wt | bias | ka [2N*128 bf16] | mg [2N*128 bf16] | qb [nd bf16]
    //   | w [2E*8 bf16] | invden [N*8 f32] | counts/row_ptr/cursor [N i32]
    //   | bsum | eidx [2E u32].  pooled ALIASES ka (dead after score pass).
    char* wsb = (char*)d_ws;
    __hip_bfloat16* Wt    = (__hip_bfloat16*)wsb;  wsb += (size_t)768 * DIM * 2;
    float* bias           = (float*)wsb;           wsb += 768 * 4;
    __hip_bfloat16* ka    = (__hip_bfloat16*)wsb;  wsb += 2 * nd * 2;
    __hip_bfloat16* mg    = (__hip_bfloat16*)wsb;  wsb += 2 * nd * 2;
    __hip_bfloat16* qb    = (__hip_bfloat16*)wsb;  wsb += nd * 2;
    __hip_bfloat16* w     = (__hip_bfloat16*)wsb;  wsb += (size_t)2 * E_EDGES * 8 * 2;
    float* invden         = (float*)wsb;           wsb += (size_t)N_NODES * 8 * 4;
    int* counts  = (int*)wsb;                      wsb += (size_t)N_NODES * 4;
    int* row_ptr = (int*)wsb;                      wsb += (size_t)N_NODES * 4;
    int* cursor  = (int*)wsb;                      wsb += (size_t)N_NODES * 4;
    int* bsum    = (int*)wsb;                      wsb += 128 * 4;
    unsigned int* eidx = (unsigned int*)wsb;
    __hip_bfloat16* pooled = ka;                   // alias: ka dead after pass A

    hipMemsetAsync(counts, 0, (size_t)N_NODES * 4, stream);

    const int scan_blocks = (N_NODES + SCAN_B - 1) / SCAN_B;   // 98
    const int edge_blocks = (2 * E_EDGES + 255) / 256;         // 3125

    // CSR chain (independent of projections)
    hist_kernel<<<dim3(edge_blocks), dim3(256), 0, stream>>>(dst0, dst1, counts);
    scanA_kernel<<<dim3(scan_blocks), dim3(SCAN_B), 0, stream>>>(counts, row_ptr, bsum);
    scanB_kernel<<<dim3(1), dim3(128), 0, stream>>>(bsum, scan_blocks);
    scanC_kernel<<<dim3(scan_blocks), dim3(SCAN_B), 0, stream>>>(row_ptr, cursor, bsum);
    scatter_kernel<<<dim3(edge_blocks), dim3(256), 0, stream>>>(
        src0, dst0, src1, dst1, cursor, eidx);

    // Projections
    fuse_weights<<<dim3(768), dim3(128), 0, stream>>>(
        Wk, bk, Wm, bm, Wq, bq, Wa, ba,
        Watt0, Wmsg0, Watt1, Wmsg1, prior0, prior1, Wt, bias);
    proj_mfma<<<dim3(PROJ_GRID), dim3(512), 0, stream>>>(
        x, Wt, bias, ka, mg, qb);

    // Split aggregation: scores (ka hot set) then weighted sum (mg hot set)
    score_kernel<<<dim3((N_NODES + 3) / 4), dim3(256), 0, stream>>>(
        (const char*)ka, (const uint2*)qb, row_ptr, counts, eidx, w, invden);
    sum_kernel<<<dim3((N_NODES + 3) / 4), dim3(256), 0, stream>>>(
        (const char*)mg, w, invden, row_ptr, counts, eidx, (uint2*)pooled);

    final_mfma<<<dim3(N_NODES / 32), dim3(256), 0, stream>>>(
        pooled, Wt, bias, x, skip, gamma, beta, out);
}

// Round 8
// 354.586 us; speedup vs baseline: 1.1335x; 1.1335x over previous
//
#include <hip/hip_runtime.h>
#include <hip/hip_bf16.h>
#include <math.h>

#define N_NODES 100000
#define DIM 128
#define NH 8
#define NC 16
#define E_EDGES 400000
#define LN_EPS 1e-3f
#define SCAN_B 1024
#define PROJ_GRID 512

typedef __attribute__((ext_vector_type(8))) short short8v;
typedef __attribute__((ext_vector_type(4))) short short4v;
typedef __attribute__((ext_vector_type(4))) float float4v;

__device__ __forceinline__ short bf16bits(float v) {
    __hip_bfloat16 b = __float2bfloat16(v);
    return *(short*)&b;
}

// unpack a uint holding 2 bf16 (lo, hi) into 2 floats
__device__ __forceinline__ void bf2x2(unsigned v, float& a, float& b) {
    a = __uint_as_float(v << 16);
    b = __uint_as_float(v & 0xffff0000u);
}

// ---------------- fused transposed weights (bf16) + fused biases -------------
// Wt[c][d], c in [0,768): sections of 128 cols:
//  0: Wk·BD(Watt0)·prior0/sqrt(C)   1: Wk·BD(Watt1)·prior1/sqrt(C)
//  2: Wm·BD(Wmsg0)                  3: Wm·BD(Wmsg1)
//  4: Wq                            5: Wa
__global__ __launch_bounds__(128) void fuse_weights(
    const float* __restrict__ Wk, const float* __restrict__ bk,
    const float* __restrict__ Wm, const float* __restrict__ bm,
    const float* __restrict__ Wq, const float* __restrict__ bq,
    const float* __restrict__ Wa, const float* __restrict__ ba,
    const float* __restrict__ Watt0, const float* __restrict__ Wmsg0,
    const float* __restrict__ Watt1, const float* __restrict__ Wmsg1,
    const float* __restrict__ prior0, const float* __restrict__ prior1,
    __hip_bfloat16* __restrict__ Wt, float* __restrict__ bias)
{
    const int c = blockIdx.x;        // 0..767
    const int d = threadIdx.x;       // 0..127
    const int sec = c >> 7, j = c & 127, h = j >> 4, l = j & 15;
    float v, b;
    if (sec == 4)      { v = Wq[d * DIM + j]; b = bq[j]; }
    else if (sec == 5) { v = Wa[d * DIM + j]; b = ba[j]; }
    else {
        const float* W1 = (sec < 2) ? Wk : Wm;
        const float* bs = (sec < 2) ? bk : bm;
        const float* W2 = (sec == 0) ? Watt0 : (sec == 1) ? Watt1
                          : (sec == 2) ? Wmsg0 : Wmsg1;
        float scale = (sec == 0) ? prior0[h] * 0.25f
                    : (sec == 1) ? prior1[h] * 0.25f : 1.f;
        float s = 0.f, sb = 0.f;
        #pragma unroll
        for (int kk = 0; kk < NC; ++kk) {
            float w2 = W2[h * 256 + kk * 16 + l];
            s  = fmaf(W1[d * DIM + h * 16 + kk], w2, s);
            sb = fmaf(bs[h * 16 + kk], w2, sb);
        }
        v = s * scale; b = sb * scale;
    }
    Wt[(size_t)c * DIM + d] = __float2bfloat16(v);
    if (d == 0) bias[c] = b;
}

// ---------------- proj: bf16 MFMA GEMM [N,128]@[128,640] ---------------------
// Persistent grid-stride kernel, 8 waves (512 thr), W register-resident.
// km row (512B) = 32 groups x 16B: group g = [ka ch 4g..4g+3 | mg ch 4g..4g+3].
// RELAXED BARRIER: raw s_barrier + lgkmcnt(0) only. __syncthreads() would
// drain vmcnt(0) (all 6 global stores + prefetch loads) every iteration --
// that store-drain was proj's 62us limiter (MfmaUtil 10%, VALU 11%, 2.5TB/s).
// The barrier only guards LDS buffer reuse; global stores may float across
// iterations. ds-read->MFMA ordering is compiler-tracked (its own lgkmcnt).
__global__ __launch_bounds__(512) void proj_mfma(
    const float* __restrict__ x,             // [N][128] fp32
    const __hip_bfloat16* __restrict__ Wt,   // [768][128]
    const float* __restrict__ bias,          // [768]
    __hip_bfloat16* __restrict__ km,         // [2N][256] group-interleaved
    __hip_bfloat16* __restrict__ qb)         // [N][128]
{
    __shared__ __align__(16) short xs[2][32 * DIM];   // 2 x 8 KB
    const int tid = threadIdx.x;
    const int wave = tid >> 6, lane = tid & 63;
    const int quad = lane >> 4, mcol = lane & 15;
    const int nt = N_NODES / 32;                      // 3125

    // ---- hoist W fragments + bias into registers (once) -------------------
    short8v wf[5][4];
    float4v bv[5];
    #pragma unroll
    for (int s = 0; s < 5; ++s) {
        const int c0 = s * 128 + wave * 16;
        const short* wp = (const short*)Wt + (size_t)(c0 + mcol) * DIM + quad * 8;
        #pragma unroll
        for (int kb = 0; kb < 4; ++kb)
            wf[s][kb] = *(const short8v*)(wp + kb * 32);
        bv[s] = *(const float4v*)(bias + c0 + quad * 4);
    }

    // ---- staging geometry: thread -> (row 0..31, 16B chunk 0..15) ----------
    const int srow = tid >> 4, sc8 = tid & 15;
    const int swz = ((sc8 ^ (srow & 7)) * 8);         // XOR-swizzled chunk

    int t = blockIdx.x;
    if (t >= nt) return;

    // prologue: stage tile t into buf0, prefetch tile t+G into regs
    float4v f0 = *(const float4v*)(x + (size_t)(t * 32 + srow) * DIM + sc8 * 8);
    float4v f1 = *(const float4v*)(x + (size_t)(t * 32 + srow) * DIM + sc8 * 8 + 4);
    {
        short8v sv;
        #pragma unroll
        for (int j = 0; j < 4; ++j) { sv[j] = bf16bits(f0[j]); sv[j + 4] = bf16bits(f1[j]); }
        *(short8v*)(xs[0] + srow * DIM + swz) = sv;
    }
    {
        int nn = t + PROJ_GRID;
        if (nn < nt) {
            f0 = *(const float4v*)(x + (size_t)(nn * 32 + srow) * DIM + sc8 * 8);
            f1 = *(const float4v*)(x + (size_t)(nn * 32 + srow) * DIM + sc8 * 8 + 4);
        }
    }

    int cur = 0;
    for (; t < nt; t += PROJ_GRID) {
        // relaxed barrier: LDS writes visible, stores NOT drained
        asm volatile("s_waitcnt lgkmcnt(0)" ::: "memory");
        __builtin_amdgcn_s_barrier();

        // B fragments (x^T) for 32 rows: node = mcol (+16), k = quad*8 + j
        short8v b0[4], b1[4];
        #pragma unroll
        for (int kb = 0; kb < 4; ++kb) {
            const int ch = ((quad + kb * 4) ^ (mcol & 7)) * 8;
            b0[kb] = *(const short8v*)(xs[cur] + mcol * DIM + ch);
            b1[kb] = *(const short8v*)(xs[cur] + (mcol + 16) * DIM + ch);
        }

        const int r0 = t * 32;

        // ---- edge-set pairs: katt (sec e) + mmsg (sec 2+e) together -------
        #pragma unroll
        for (int e = 0; e < 2; ++e) {
            float4v aK0 = {0.f,0.f,0.f,0.f}, aK1 = {0.f,0.f,0.f,0.f};
            float4v aM0 = {0.f,0.f,0.f,0.f}, aM1 = {0.f,0.f,0.f,0.f};
            #pragma unroll
            for (int kb = 0; kb < 4; ++kb) {
                aK0 = __builtin_amdgcn_mfma_f32_16x16x32_bf16(wf[e][kb],     b0[kb], aK0, 0, 0, 0);
                aK1 = __builtin_amdgcn_mfma_f32_16x16x32_bf16(wf[e][kb],     b1[kb], aK1, 0, 0, 0);
                aM0 = __builtin_amdgcn_mfma_f32_16x16x32_bf16(wf[2 + e][kb], b0[kb], aM0, 0, 0, 0);
                aM1 = __builtin_amdgcn_mfma_f32_16x16x32_bf16(wf[2 + e][kb], b1[kb], aM1, 0, 0, 0);
            }
            short8v o0, o1;
            #pragma unroll
            for (int g = 0; g < 4; ++g) {
                o0[g]     = bf16bits(aK0[g] + bv[e][g]);
                o0[g + 4] = bf16bits(aM0[g] + bv[2 + e][g]);
                o1[g]     = bf16bits(aK1[g] + bv[e][g]);
                o1[g + 4] = bf16bits(aM1[g] + bv[2 + e][g]);
            }
            short* dp = (short*)km
                      + ((size_t)(r0 + mcol) + (size_t)e * N_NODES) * 256
                      + (wave * 4 + quad) * 8;
            *(short8v*)dp              = o0;
            *(short8v*)(dp + 16 * 256) = o1;
        }

        // ---- q section --------------------------------------------------
        {
            float4v a0v = {0.f,0.f,0.f,0.f}, a1v = {0.f,0.f,0.f,0.f};
            #pragma unroll
            for (int kb = 0; kb < 4; ++kb) {
                a0v = __builtin_amdgcn_mfma_f32_16x16x32_bf16(wf[4][kb], b0[kb], a0v, 0, 0, 0);
                a1v = __builtin_amdgcn_mfma_f32_16x16x32_bf16(wf[4][kb], b1[kb], a1v, 0, 0, 0);
            }
            short4v o0, o1;
            #pragma unroll
            for (int g = 0; g < 4; ++g) {
                o0[g] = bf16bits(a0v[g] + bv[4][g]);
                o1[g] = bf16bits(a1v[g] + bv[4][g]);
            }
            short* dp = (short*)qb + (size_t)(r0 + mcol) * DIM + wave * 16 + quad * 4;
            *(short4v*)dp              = o0;
            *(short4v*)(dp + 16 * DIM) = o1;
        }

        // stage tile t+G (already in f0/f1) into buf[cur^1]; prefetch t+2G
        int nn = t + PROJ_GRID;
        if (nn < nt) {
            short8v sv;
            #pragma unroll
            for (int j = 0; j < 4; ++j) { sv[j] = bf16bits(f0[j]); sv[j + 4] = bf16bits(f1[j]); }
            *(short8v*)(xs[cur ^ 1] + srow * DIM + swz) = sv;
            int n2 = nn + PROJ_GRID;
            if (n2 < nt) {
                f0 = *(const float4v*)(x + (size_t)(n2 * 32 + srow) * DIM + sc8 * 8);
                f1 = *(const float4v*)(x + (size_t)(n2 * 32 + srow) * DIM + sc8 * 8 + 4);
            }
        }
        cur ^= 1;
    }
}

// ---------------- CSR build ----------------
__global__ __launch_bounds__(256) void hist_kernel(
    const int* __restrict__ dst0, const int* __restrict__ dst1,
    int* __restrict__ counts)
{
    int e = blockIdx.x * 256 + threadIdx.x;
    if (e < E_EDGES) atomicAdd(&counts[dst0[e]], 1);
    int e1 = e - E_EDGES;
    if (e1 >= 0 && e1 < E_EDGES) atomicAdd(&counts[dst1[e1]], 1);
}

__global__ __launch_bounds__(SCAN_B) void scanA_kernel(
    const int* __restrict__ counts, int* __restrict__ row_ptr,
    int* __restrict__ bsum)
{
    __shared__ int buf[2][SCAN_B];
    int i = blockIdx.x * SCAN_B + threadIdx.x;
    int v = (i < N_NODES) ? counts[i] : 0;
    int cur = 0;
    buf[0][threadIdx.x] = v;
    __syncthreads();
    #pragma unroll
    for (int off = 1; off < SCAN_B; off <<= 1) {
        int t = buf[cur][threadIdx.x];
        int add = (threadIdx.x >= off) ? buf[cur][threadIdx.x - off] : 0;
        buf[cur ^ 1][threadIdx.x] = t + add;
        cur ^= 1;
        __syncthreads();
    }
    int inc = buf[cur][threadIdx.x];
    if (i < N_NODES) row_ptr[i] = inc - v;
    if (threadIdx.x == SCAN_B - 1) bsum[blockIdx.x] = inc;
}

// parallel exclusive scan of the (<=128) block sums, single block
__global__ __launch_bounds__(128) void scanB_kernel(int* __restrict__ bsum, int nblocks)
{
    __shared__ int buf[2][128];
    int t = threadIdx.x;
    int v = (t < nblocks) ? bsum[t] : 0;
    buf[0][t] = v;
    __syncthreads();
    int cur = 0;
    #pragma unroll
    for (int off = 1; off < 128; off <<= 1) {
        int a = buf[cur][t];
        if (t >= off) a += buf[cur][t - off];
        buf[cur ^ 1][t] = a;
        cur ^= 1;
        __syncthreads();
    }
    if (t < nblocks) bsum[t] = buf[cur][t] - v;   // exclusive
}

__global__ __launch_bounds__(SCAN_B) void scanC_kernel(
    int* __restrict__ row_ptr, int* __restrict__ cursor,
    const int* __restrict__ bsum)
{
    int i = blockIdx.x * SCAN_B + threadIdx.x;
    if (i < N_NODES) {
        int r = row_ptr[i] + bsum[blockIdx.x];
        row_ptr[i] = r;
        cursor[i] = r;
    }
}

__global__ __launch_bounds__(256) void scatter_kernel(
    const int* __restrict__ src0, const int* __restrict__ dst0,
    const int* __restrict__ src1, const int* __restrict__ dst1,
    int* __restrict__ cursor, unsigned int* __restrict__ eidx)
{
    int e = blockIdx.x * 256 + threadIdx.x;
    if (e < E_EDGES) {
        int d = dst0[e];
        int pos = atomicAdd(&cursor[d], 1);
        eidx[pos] = (unsigned int)src0[e];
    }
    int e1 = e - E_EDGES;
    if (e1 >= 0 && e1 < E_EDGES) {
        int d = dst1[e1];
        int pos = atomicAdd(&cursor[d], 1);
        eidx[pos] = (unsigned int)(src1[e1] + N_NODES);
    }
}

// ---------------- aggregation: one wave per node, PAIR of edges per step -----
// Lanes 0-31 process edge e0, lanes 32-63 edge e1. Lane loads ONE uint4
// (16B group: ka 4ch | mg 4ch). Score reduce = shfl_xor 1,2 (4 lanes/head,
// DPP-cheap). Cross-half combine of den/acc happens ONCE per node.
__global__ __launch_bounds__(256) void agg_kernel(
    const char* __restrict__ km,        // [2N][512B] group-interleaved
    const uint2* __restrict__ qv,       // [N][32] uint2 (ch quad per lane)
    const int* __restrict__ row_ptr, const int* __restrict__ counts,
    const unsigned int* __restrict__ eidx,
    uint2* __restrict__ pooled)         // [N][32] uint2
{
    const int wave = threadIdx.x >> 6, lane = threadIdx.x & 63;
    const int n = blockIdx.x * 4 + wave;
    if (n >= N_NODES) return;
    const int start = row_ptr[n], cnt = counts[n];
    const int hi = lane >> 5;           // 0: edge e0, 1: edge e1
    const int glane = lane & 31;
    const unsigned g16 = (unsigned)glane << 4;

    uint2 qu = qv[(size_t)n * 32 + glane];
    float q0, q1, q2, q3;
    bf2x2(qu.x, q0, q1); bf2x2(qu.y, q2, q3);

    float a0 = 0.f, a1 = 0.f, a2 = 0.f, a3 = 0.f, den = 0.f;

#define PAIR_ACC(u)                                                          \
    {                                                                        \
        float k0, k1, k2, k3, m0, m1, m2, m3;                                \
        bf2x2((u).x, k0, k1); bf2x2((u).y, k2, k3);                          \
        bf2x2((u).z, m0, m1); bf2x2((u).w, m2, m3);                          \
        float p = fmaf(k3, q3, fmaf(k2, q2, fmaf(k1, q1, k0 * q0)));         \
        p += __shfl_xor(p, 1, 64);                                           \
        p += __shfl_xor(p, 2, 64);                                           \
        float e = __expf(p);                                                 \
        den += e;                                                            \
        a0 = fmaf(e, m0, a0); a1 = fmaf(e, m1, a1);                          \
        a2 = fmaf(e, m2, a2); a3 = fmaf(e, m3, a3);                          \
    }

    int i = 0;
    for (; i + 8 <= cnt; i += 8) {
        unsigned ra = eidx[start + i + hi];
        unsigned rb = eidx[start + i + 2 + hi];
        unsigned rc = eidx[start + i + 4 + hi];
        unsigned rd = eidx[start + i + 6 + hi];
        uint4 ua = *(const uint4*)(km + (((size_t)ra << 9) | g16));
        uint4 ub = *(const uint4*)(km + (((size_t)rb << 9) | g16));
        uint4 uc = *(const uint4*)(km + (((size_t)rc << 9) | g16));
        uint4 ud = *(const uint4*)(km + (((size_t)rd << 9) | g16));
        PAIR_ACC(ua); PAIR_ACC(ub); PAIR_ACC(uc); PAIR_ACC(ud);
    }
    for (; i + 2 <= cnt; i += 2) {
        unsigned ra = eidx[start + i + hi];
        uint4 ua = *(const uint4*)(km + (((size_t)ra << 9) | g16));
        PAIR_ACC(ua);
    }
    if (i < cnt) {   // odd tail: both halves load the edge, hi contributes 0
        unsigned ra = eidx[start + i];
        uint4 ua = *(const uint4*)(km + (((size_t)ra << 9) | g16));
        float k0, k1, k2, k3, m0, m1, m2, m3;
        bf2x2(ua.x, k0, k1); bf2x2(ua.y, k2, k3);
        bf2x2(ua.z, m0, m1); bf2x2(ua.w, m2, m3);
        float p = fmaf(k3, q3, fmaf(k2, q2, fmaf(k1, q1, k0 * q0)));
        p += __shfl_xor(p, 1, 64);
        p += __shfl_xor(p, 2, 64);
        float e = hi ? 0.f : __expf(p);
        den += e;
        a0 = fmaf(e, m0, a0); a1 = fmaf(e, m1, a1);
        a2 = fmaf(e, m2, a2); a3 = fmaf(e, m3, a3);
    }
#undef PAIR_ACC

    // combine the two edge-halves (same channel ownership, disjoint edges)
    den += __shfl_xor(den, 32, 64);
    a0 += __shfl_xor(a0, 32, 64);
    a1 += __shfl_xor(a1, 32, 64);
    a2 += __shfl_xor(a2, 32, 64);
    a3 += __shfl_xor(a3, 32, 64);

    float inv = (den > 0.f) ? (1.f / den) : 0.f;
    float v0 = a0 * inv, v1 = a1 * inv, v2 = a2 * inv, v3 = a3 * inv;

    // 2 erf/lane: lo half gelus (v0,v1), hi half gelus (v2,v3); swap via shfl
    float s0 = hi ? v2 : v0;
    float s1 = hi ? v3 : v1;
    s0 = 0.5f * s0 * (1.f + erff(s0 * 0.70710678118654752f));
    s1 = 0.5f * s1 * (1.f + erff(s1 * 0.70710678118654752f));
    unsigned pk = ((unsigned)(unsigned short)bf16bits(s0))
                | ((unsigned)(unsigned short)bf16bits(s1) << 16);
    unsigned ph = __shfl_xor(pk, 32, 64);
    if (!hi) {
        uint2 o; o.x = pk; o.y = ph;
        pooled[(size_t)n * 32 + glane] = o;
    }
}

// ---------------- final: MFMA GEMM(Wa) -> skip -> LayerNorm ------------------
__global__ __launch_bounds__(256) void final_mfma(
    const __hip_bfloat16* __restrict__ pooled,  // [N][128] bf16, gelu applied
    const __hip_bfloat16* __restrict__ Wt,      // [768][128]; rows 640.. = Wa^T
    const float* __restrict__ bias,             // [768]; 640.. = ba
    const float* __restrict__ x,
    const float* __restrict__ skip, const float* __restrict__ gamma,
    const float* __restrict__ beta, float* __restrict__ out)
{
    __shared__ float hs[32][DIM];
    const int wave = threadIdx.x >> 6, lane = threadIdx.x & 63;
    const int quad = lane >> 4, mcol = lane & 15;
    const int r0 = blockIdx.x * 32;

    short8v a0[4], a1[4];
    const short* pp0 = (const short*)pooled + (size_t)(r0 + mcol) * DIM + quad * 8;
    const short* pp1 = pp0 + 16 * DIM;
    #pragma unroll
    for (int kb = 0; kb < 4; ++kb) {
        a0[kb] = *(const short8v*)(pp0 + kb * 32);
        a1[kb] = *(const short8v*)(pp1 + kb * 32);
    }
    const float alpha = 1.f / (1.f + expf(-skip[0]));

    #pragma unroll
    for (int t = 0; t < 2; ++t) {
        const int c0 = wave * 32 + t * 16;
        const short* wp = (const short*)Wt + (size_t)(640 + c0 + mcol) * DIM + quad * 8;
        float4v acc0 = {0.f, 0.f, 0.f, 0.f};
        float4v acc1 = {0.f, 0.f, 0.f, 0.f};
        #pragma unroll
        for (int kb = 0; kb < 4; ++kb) {
            short8v bfr = *(const short8v*)(wp + kb * 32);
            acc0 = __builtin_amdgcn_mfma_f32_16x16x32_bf16(a0[kb], bfr, acc0, 0, 0, 0);
            acc1 = __builtin_amdgcn_mfma_f32_16x16x32_bf16(a1[kb], bfr, acc1, 0, 0, 0);
        }
        const float bcol = bias[640 + c0 + mcol];
        const int cc = c0 + mcol;
        const int rq = quad * 4;
        #pragma unroll
        for (int g = 0; g < 4; ++g) {
            int rA = rq + g, rB = rq + 16 + g;
            hs[rA][cc] = alpha * (acc0[g] + bcol)
                       + (1.f - alpha) * x[(size_t)(r0 + rA) * DIM + cc];
            hs[rB][cc] = alpha * (acc1[g] + bcol)
                       + (1.f - alpha) * x[(size_t)(r0 + rB) * DIM + cc];
        }
    }
    __syncthreads();

    float gam0 = gamma[lane], gam1 = gamma[lane + 64];
    float bet0 = beta[lane],  bet1 = beta[lane + 64];
    for (int r = wave; r < 32; r += 4) {
        int row = r0 + r;
        float v0 = hs[r][lane], v1 = hs[r][lane + 64];
        float s = v0 + v1, s2 = v0 * v0 + v1 * v1;
        #pragma unroll
        for (int off = 1; off < 64; off <<= 1) {
            s  += __shfl_xor(s,  off, 64);
            s2 += __shfl_xor(s2, off, 64);
        }
        float mu = s * (1.f / 128.f);
        float var = s2 * (1.f / 128.f) - mu * mu;
        float rstd = rsqrtf(var + LN_EPS);
        out[(size_t)row * DIM + lane]      = (v0 - mu) * rstd * gam0 + bet0;
        out[(size_t)row * DIM + lane + 64] = (v1 - mu) * rstd * gam1 + bet1;
    }
}

extern "C" void kernel_launch(void* const* d_in, const int* in_sizes, int n_in,
                              void* d_out, int out_size, void* d_ws, size_t ws_size,
                              hipStream_t stream) {
    const float* x     = (const float*)d_in[0];
    const int*   src0  = (const int*)d_in[1];
    const int*   dst0  = (const int*)d_in[2];
    const int*   src1  = (const int*)d_in[3];
    const int*   dst1  = (const int*)d_in[4];
    const float* Wk    = (const float*)d_in[5];
    const float* bk    = (const float*)d_in[6];
    const float* Wm    = (const float*)d_in[7];
    const float* bm    = (const float*)d_in[8];
    const float* Wq    = (const float*)d_in[9];
    const float* bq    = (const float*)d_in[10];
    const float* Wa    = (const float*)d_in[11];
    const float* ba    = (const float*)d_in[12];
    const float* Watt0 = (const float*)d_in[13];
    const float* Wmsg0 = (const float*)d_in[14];
    const float* Watt1 = (const float*)d_in[15];
    const float* Wmsg1 = (const float*)d_in[16];
    const float* prior0= (const float*)d_in[17];
    const float* prior1= (const float*)d_in[18];
    const float* skip  = (const float*)d_in[19];
    const float* gamma = (const float*)d_in[20];
    const float* beta  = (const float*)d_in[21];
    float* out = (float*)d_out;

    const size_t nd = (size_t)N_NODES * DIM;
    // Workspace (~158 MB):
    //   Wt [768*128 bf16] | bias [768 f32] | km [2N*256 bf16 group-interleaved]
    //   | qb [nd bf16] | pooled [nd bf16] | counts/row_ptr/cursor [N i32]
    //   | bsum [128 i32] | eidx [2E u32]
    char* wsb = (char*)d_ws;
    __hip_bfloat16* Wt    = (__hip_bfloat16*)wsb;  wsb += (size_t)768 * DIM * 2;
    float* bias           = (float*)wsb;           wsb += 768 * 4;
    __hip_bfloat16* km    = (__hip_bfloat16*)wsb;  wsb += (size_t)2 * N_NODES * 256 * 2;
    __hip_bfloat16* qb    = (__hip_bfloat16*)wsb;  wsb += nd * 2;
    __hip_bfloat16* pooled= (__hip_bfloat16*)wsb;  wsb += nd * 2;
    int* counts  = (int*)wsb;                      wsb += (size_t)N_NODES * 4;
    int* row_ptr = (int*)wsb;                      wsb += (size_t)N_NODES * 4;
    int* cursor  = (int*)wsb;                      wsb += (size_t)N_NODES * 4;
    int* bsum    = (int*)wsb;                      wsb += 128 * 4;
    unsigned int* eidx = (unsigned int*)wsb;

    hipMemsetAsync(counts, 0, (size_t)N_NODES * 4, stream);

    const int scan_blocks = (N_NODES + SCAN_B - 1) / SCAN_B;   // 98
    const int edge_blocks = (2 * E_EDGES + 255) / 256;         // 3125

    // CSR chain (independent of projections)
    hist_kernel<<<dim3(edge_blocks), dim3(256), 0, stream>>>(dst0, dst1, counts);
    scanA_kernel<<<dim3(scan_blocks), dim3(SCAN_B), 0, stream>>>(counts, row_ptr, bsum);
    scanB_kernel<<<dim3(1), dim3(128), 0, stream>>>(bsum, scan_blocks);
    scanC_kernel<<<dim3(scan_blocks), dim3(SCAN_B), 0, stream>>>(row_ptr, cursor, bsum);
    scatter_kernel<<<dim3(edge_blocks), dim3(256), 0, stream>>>(
        src0, dst0, src1, dst1, cursor, eidx);

    // Projections
    fuse_weights<<<dim3(768), dim3(128), 0, stream>>>(
        Wk, bk, Wm, bm, Wq, bq, Wa, ba,
        Watt0, Wmsg0, Watt1, Wmsg1, prior0, prior1, Wt, bias);
    proj_mfma<<<dim3(PROJ_GRID), dim3(512), 0, stream>>>(
        x, Wt, bias, km, qb);

    agg_kernel<<<dim3((N_NODES + 3) / 4), dim3(256), 0, stream>>>(
        (const char*)km, (const uint2*)qb, row_ptr, counts, eidx,
        (uint2*)pooled);

    final_mfma<<<dim3(N_NODES / 32), dim3(256), 0, stream>>>(
        pooled, Wt, bias, x, skip, gamma, beta, out);
}